// Round 13
// baseline (82.670 us; speedup 1.0000x reference)
//
#include <hip/hip_runtime.h>
#include <hip/hip_bf16.h>

#define TSEQ 2048
#define BATCH 8
#define NHEAD 4
#define BH (BATCH*NHEAD)
#define HD 32
#define SCALE 0.17677669529663687f   /* 1/sqrt(32) */
#define L2E   1.4426950408889634f
#define SCALE2 (SCALE * L2E)
#define LAMBDA_INIT 0.8f
#define LN_EPS 1e-5f

#if __has_builtin(__builtin_amdgcn_exp2f)
#define EXP2F(x) __builtin_amdgcn_exp2f(x)
#else
#define EXP2F(x) __expf((x) * 0.6931471805599453f)
#endif

typedef __attribute__((ext_vector_type(8))) short short8;
typedef __attribute__((ext_vector_type(4))) float f32x4;

// native bf16 convert (RTNE) — compiler emits v_cvt_pk_bf16_f32 pairs
static __device__ __forceinline__ unsigned short f2bf(float x) {
    union { __hip_bfloat16 h; unsigned short u; } cv;
    cv.h = __float2bfloat16(x);
    return cv.u;
}

// ---------------- Kernel P: weight transpose + bf16 cast + scalars ------
__global__ __launch_bounds__(256) void k_prep(
    const float* __restrict__ wq, const float* __restrict__ wk,
    const float* __restrict__ wv, const float* __restrict__ wo,
    const float* __restrict__ lq1, const float* __restrict__ lk1,
    const float* __restrict__ lq2, const float* __restrict__ lk2,
    const float* __restrict__ sig_s_p, const float* __restrict__ sig_n_p,
    unsigned short* __restrict__ WqkvT, unsigned short* __restrict__ WoT,
    float* __restrict__ scal)
{
    __shared__ float xt[64][65];
    const int bid = blockIdx.x, tid = threadIdx.x;

    if (bid == 0 && tid == 0) {
        float d1 = 0.f, d2 = 0.f;
        for (int i = 0; i < HD; i++) { d1 += lq1[i] * lk1[i]; d2 += lq2[i] * lk2[i]; }
        float lam = __expf(d1) - __expf(d2) + LAMBDA_INIT;
        float ss = fmaxf(sig_s_p[0], 1.f);
        float sn = fmaxf(sig_n_p[0], 1.f);
        int W = (int)ceilf(fmaxf(ss, sn) * 6.f);
        W = (W + 31) & ~31;
        if (W < 64) W = 64;
        scal[0] = lam;
        scal[1] = -0.5f / (ss * ss) * L2E;   // pre-scaled for exp2
        scal[2] = -0.5f / (sn * sn) * L2E;
        scal[3] = (float)W;
    }

    const float* src; int srcN, k0, nsrc0, dstK;
    unsigned short* dst;
    if (bid < 24) {
        int ntile = bid >> 1, ktile = bid & 1;
        int gn0 = ntile * 64; k0 = ktile * 64;
        int mat = gn0 >> 8;
        src = (mat == 0) ? wq : (mat == 1 ? wk : wv);
        srcN = 256; nsrc0 = gn0 & 255;
        dst = WqkvT + (size_t)gn0 * 128; dstK = 128;
    } else {
        int b2 = bid - 24;
        int ntile = b2 >> 2, ktile = b2 & 3;
        int gn0 = ntile * 64; k0 = ktile * 64;
        src = wo; srcN = 128; nsrc0 = gn0;
        dst = WoT + (size_t)gn0 * 256; dstK = 256;
    }
    {
        int r = tid >> 2, cs = tid & 3;
        const float* sp = src + (size_t)(k0 + r) * srcN + nsrc0 + cs * 16;
        #pragma unroll
        for (int j = 0; j < 4; j++) {
            float4 v = *(const float4*)(sp + j * 4);
            xt[r][cs * 16 + j * 4 + 0] = v.x;
            xt[r][cs * 16 + j * 4 + 1] = v.y;
            xt[r][cs * 16 + j * 4 + 2] = v.z;
            xt[r][cs * 16 + j * 4 + 3] = v.w;
        }
    }
    __syncthreads();
    {
        int n = tid >> 2, ks = tid & 3;
        short8 o0, o1;
        #pragma unroll
        for (int j = 0; j < 8; j++) {
            o0[j] = (short)f2bf(xt[ks * 16 + j][n]);
            o1[j] = (short)f2bf(xt[ks * 16 + 8 + j][n]);
        }
        unsigned short* dp = dst + (size_t)n * dstK + k0 + ks * 16;
        *(short8*)dp = o0;
        *(short8*)(dp + 8) = o1;
    }
}

// ---------------- Kernel A: LayerNorm + QKV projection (MFMA) ----------
__global__ __launch_bounds__(256) void k_qkv(
    const float* __restrict__ tokens, const float* __restrict__ ln_w,
    const float* __restrict__ ln_b, const unsigned short* __restrict__ WqkvT,
    unsigned short* __restrict__ Qg, unsigned short* __restrict__ Kg,
    unsigned short* __restrict__ Vtg)
{
    __shared__ unsigned short x_lds[32][132];
    __shared__ unsigned short c_lds[4][16][68];
    const int tid = threadIdx.x;
    const int r0 = blockIdx.x * 32;

    {
        int row = tid >> 3, sub = tid & 7;
        const float* tr = tokens + (size_t)(r0 + row) * 128 + sub * 16;
        float v[16]; float s = 0.f, sq = 0.f;
        #pragma unroll
        for (int j = 0; j < 16; j += 4) {
            float4 t4 = *(const float4*)(tr + j);
            v[j] = t4.x; v[j + 1] = t4.y; v[j + 2] = t4.z; v[j + 3] = t4.w;
        }
        #pragma unroll
        for (int j = 0; j < 16; j++) { s += v[j]; sq += v[j] * v[j]; }
        #pragma unroll
        for (int m = 1; m < 8; m <<= 1) { s += __shfl_xor(s, m, 64); sq += __shfl_xor(sq, m, 64); }
        float mean = s * (1.f / 128.f);
        float var  = sq * (1.f / 128.f) - mean * mean;
        float rstd = rsqrtf(var + LN_EPS);
        short8 o0, o1;
        #pragma unroll
        for (int j = 0; j < 8; j++) {
            int c0 = sub * 16 + j, c1 = sub * 16 + 8 + j;
            o0[j] = (short)f2bf((v[j] - mean) * rstd * ln_w[c0] + ln_b[c0]);
            o1[j] = (short)f2bf((v[8 + j] - mean) * rstd * ln_w[c1] + ln_b[c1]);
        }
        *(short8*)&x_lds[row][sub * 16] = o0;
        *(short8*)&x_lds[row][sub * 16 + 8] = o1;
    }
    __syncthreads();

    const int w = tid >> 6, lane = tid & 63;
    const int lg = lane >> 4, li = lane & 15;
    const int rt = w >> 1, ch = w & 1;

    short8 a[4];
    #pragma unroll
    for (int kc = 0; kc < 4; kc++)
        a[kc] = *(const short8*)&x_lds[rt * 16 + li][kc * 32 + lg * 8];

    const int b   = r0 >> 11;
    const int tw0 = (r0 & 2047) + rt * 16;

    #pragma unroll
    for (int cc = 0; cc < 6; cc++) {
        f32x4 acc[4] = {};
        #pragma unroll
        for (int t = 0; t < 4; t++) {
            int n0 = ch * 384 + cc * 64 + t * 16;
            const unsigned short* bp = WqkvT + (size_t)(n0 + li) * 128 + lg * 8;
            #pragma unroll
            for (int kc = 0; kc < 4; kc++) {
                short8 bf = *(const short8*)(bp + kc * 32);
                acc[t] = __builtin_amdgcn_mfma_f32_16x16x32_bf16(a[kc], bf, acc[t], 0, 0, 0);
            }
        }
        #pragma unroll
        for (int t = 0; t < 4; t++)
            #pragma unroll
            for (int r = 0; r < 4; r++)
                c_lds[w][lg * 4 + r][t * 16 + li] = f2bf(acc[t][r]);

        int gc = ch * 6 + cc;
        int kind = gc >> 2, h = gc & 3;
        size_t bhh = (size_t)(b * NHEAD + h);
        if (kind < 2) {
            unsigned short* base = (kind == 0) ? Qg : Kg;
            int row = lane >> 2, seg = lane & 3;
            unsigned short* dp = base + (bhh * TSEQ + tw0 + row) * 64 + seg * 16;
            *(short8*)dp       = *(const short8*)&c_lds[w][row][seg * 16];
            *(short8*)(dp + 8) = *(const short8*)&c_lds[w][row][seg * 16 + 8];
        } else {
            int d = lane;
            short8 v0, v1;
            #pragma unroll
            for (int j = 0; j < 8; j++) {
                v0[j] = (short)c_lds[w][j][d];
                v1[j] = (short)c_lds[w][8 + j][d];
            }
            unsigned short* dp = Vtg + (bhh * 64 + d) * TSEQ + tw0;
            *(short8*)dp = v0;
            *(short8*)(dp + 8) = v1;
        }
    }
}

// ---- Kernel B: fused banded differential attention + wo projection ----
// R8 structure (single K prefetch, V in-iteration) + __launch_bounds__(256,4):
// 128-VGPR cap -> 4 waves/SIMD resident (2x the ~190-VGPR default's 2/SIMD).
// Latency-bound kernel (R8-R12 all null on instruction stream) -> occupancy
// is the remaining lever. If it spills, counters show it (R10 lesson).
__global__ __launch_bounds__(256, 4) void k_attn2(
    const unsigned short* __restrict__ Qg, const unsigned short* __restrict__ Kg,
    const unsigned short* __restrict__ Vtg,
    const float* __restrict__ scal,
    const float* __restrict__ hn_w, const float* __restrict__ hn_b,
    const unsigned short* __restrict__ WoT, const float* __restrict__ tokens,
    float* __restrict__ out)
{
    __shared__ unsigned short p_lds[4][2][32][36];
    __shared__ unsigned short ao[32][264];

    const int tid  = threadIdx.x;
    const int w    = tid >> 6;        // wave = head
    const int lane = tid & 63;
    const int lg   = lane >> 4;
    const int li   = lane & 15;

    const int b  = blockIdx.x & 7;    // XCD-aware: batch pinned to XCD
    const int qw = (blockIdx.x >> 3) * 32;
    const int bh = b * NHEAD + w;

    const float lam = scal[0];
    const float c1  = scal[1];        // includes log2(e)
    const float c2  = scal[2];
    const int   W   = (int)scal[3];

    int lo = qw - W; if (lo < 0) lo = 0; lo &= ~31;
    int hi = qw + 32 + W; hi = (hi + 31) & ~31; if (hi > TSEQ) hi = TSEQ;

    short8 q1[2], q2[2];
    #pragma unroll
    for (int qt = 0; qt < 2; qt++) {
        const unsigned short* qp = Qg + ((size_t)bh * TSEQ + (qw + qt * 16 + li)) * 64;
        q1[qt] = *(const short8*)(qp + lg * 8);
        q2[qt] = *(const short8*)(qp + 32 + lg * 8);
    }

    const unsigned short* kbase = Kg  + ((size_t)bh * TSEQ + li) * 64 + lg * 8;
    const unsigned short* vbase = Vtg + ((size_t)bh * 64 + li) * TSEQ + lg * 8;

    f32x4 acc1[2][4] = {}, acc2[2][4] = {};
    float ls1[2][4] = {}, ls2[2][4] = {};
    const f32x4 zero4 = {0.f, 0.f, 0.f, 0.f};

    // prefetch K(lo)
    short8 kf1c[2], kf2c[2];
    {
        const unsigned short* kp = kbase + (size_t)lo * 64;
        kf1c[0] = *(const short8*)(kp);
        kf2c[0] = *(const short8*)(kp + 32);
        kf1c[1] = *(const short8*)(kp + 1024);
        kf2c[1] = *(const short8*)(kp + 1024 + 32);
    }

    for (int kv = lo; kv < hi; kv += 32) {
        // V(kv) issued early: latency hides under QK + exp
        const unsigned short* vp = vbase + kv;
        short8 vf[4];
        #pragma unroll
        for (int dt = 0; dt < 4; dt++)
            vf[dt] = *(const short8*)(vp + (size_t)dt * 16 * TSEQ);

        // K(kv+32) prefetch (uniform predicate)
        short8 kf1n[2], kf2n[2];
        if (kv + 32 < hi) {
            const unsigned short* kp = kbase + (size_t)(kv + 32) * 64;
            kf1n[0] = *(const short8*)(kp);
            kf2n[0] = *(const short8*)(kp + 32);
            kf1n[1] = *(const short8*)(kp + 1024);
            kf2n[1] = *(const short8*)(kp + 1024 + 32);
        }

        #pragma unroll
        for (int qt = 0; qt < 2; qt++) {
            f32x4 s1[2], s2[2];
            #pragma unroll
            for (int kt = 0; kt < 2; kt++) {
                s1[kt] = __builtin_amdgcn_mfma_f32_16x16x32_bf16(q1[qt], kf1c[kt], zero4, 0, 0, 0);
                s2[kt] = __builtin_amdgcn_mfma_f32_16x16x32_bf16(q2[qt], kf2c[kt], zero4, 0, 0, 0);
            }
            const float rb = (float)(kv + li - qw - qt * 16 - 4 * lg);
            #pragma unroll
            for (int kt = 0; kt < 2; kt++) {
                #pragma unroll
                for (int r = 0; r < 4; r++) {
                    float rel = rb + (float)(16 * kt - r);
                    float rr  = rel * rel;
                    float e1  = EXP2F(fmaf(s1[kt][r], SCALE2, c1 * rr));
                    float e2  = EXP2F(fmaf(s2[kt][r], SCALE2, c2 * rr));
                    ls1[qt][r] += e1;
                    ls2[qt][r] += e2;
                    p_lds[w][0][qt * 16 + lg * 4 + r][kt * 16 + li] = f2bf(e1);
                    p_lds[w][1][qt * 16 + lg * 4 + r][kt * 16 + li] = f2bf(e2);
                }
            }
        }

        #pragma unroll
        for (int qt = 0; qt < 2; qt++) {
            short8 pa1 = *(const short8*)&p_lds[w][0][qt * 16 + li][lg * 8];
            short8 pa2 = *(const short8*)&p_lds[w][1][qt * 16 + li][lg * 8];
            #pragma unroll
            for (int dt = 0; dt < 4; dt++) {
                acc1[qt][dt] = __builtin_amdgcn_mfma_f32_16x16x32_bf16(pa1, vf[dt], acc1[qt][dt], 0, 0, 0);
                acc2[qt][dt] = __builtin_amdgcn_mfma_f32_16x16x32_bf16(pa2, vf[dt], acc2[qt][dt], 0, 0, 0);
            }
        }

        kf1c[0] = kf1n[0]; kf1c[1] = kf1n[1];
        kf2c[0] = kf2n[0]; kf2c[1] = kf2n[1];
    }

    #pragma unroll
    for (int qt = 0; qt < 2; qt++)
        #pragma unroll
        for (int r = 0; r < 4; r++) {
            #pragma unroll
            for (int m = 1; m < 16; m <<= 1) {
                ls1[qt][r] += __shfl_xor(ls1[qt][r], m, 64);
                ls2[qt][r] += __shfl_xor(ls2[qt][r], m, 64);
            }
        }

    {
        float hw[4], hb[4];
        #pragma unroll
        for (int t = 0; t < 4; t++) { hw[t] = hn_w[t * 16 + li]; hb[t] = hn_b[t * 16 + li]; }

        #pragma unroll
        for (int qt = 0; qt < 2; qt++) {
            #pragma unroll
            for (int r = 0; r < 4; r++) {
                float il1 = 1.f / ls1[qt][r];
                float il2 = lam / ls2[qt][r];
                float o[4];
                float s = 0.f, sq = 0.f;
                #pragma unroll
                for (int t = 0; t < 4; t++) {
                    o[t] = acc1[qt][t][r] * il1 - acc2[qt][t][r] * il2;
                    s += o[t]; sq += o[t] * o[t];
                }
                #pragma unroll
                for (int m = 1; m < 16; m <<= 1) { s += __shfl_xor(s, m, 64); sq += __shfl_xor(sq, m, 64); }
                float mean = s * (1.f / 64.f);
                float var  = sq * (1.f / 64.f) - mean * mean;
                float rstd = rsqrtf(var + LN_EPS);
                int arow = qt * 16 + lg * 4 + r;
                #pragma unroll
                for (int t = 0; t < 4; t++) {
                    ao[arow][w * 64 + t * 16 + li] =
                        f2bf(((o[t] - mean) * rstd * hw[t] + hb[t]) * 0.2f);
                }
            }
        }
    }
    __syncthreads();

    // ---- wo GEMM: 32 rows x 256 k x 128 cols; wave w does cols [w*32, w*32+32)
    const int row0 = b * TSEQ + qw;
    #pragma unroll
    for (int c2 = 0; c2 < 2; c2++) {
        const int ct = w * 2 + c2;
        short8 bfr[8];
        const unsigned short* bp = WoT + (size_t)(ct * 16 + li) * 256 + lg * 8;
        #pragma unroll
        for (int kc = 0; kc < 8; kc++) bfr[kc] = *(const short8*)(bp + kc * 32);

        #pragma unroll
        for (int qt = 0; qt < 2; qt++) {
            f32x4 acc = {};
            #pragma unroll
            for (int kc = 0; kc < 8; kc++) {
                short8 af = *(const short8*)&ao[qt * 16 + li][kc * 32 + lg * 8];
                acc = __builtin_amdgcn_mfma_f32_16x16x32_bf16(af, bfr[kc], acc, 0, 0, 0);
            }
            #pragma unroll
            for (int r = 0; r < 4; r++) {
                size_t idx = (size_t)(row0 + qt * 16 + lg * 4 + r) * 128 + ct * 16 + li;
                out[idx] = tokens[idx] + acc[r];
            }
        }
    }
}

extern "C" void kernel_launch(void* const* d_in, const int* in_sizes, int n_in,
                              void* d_out, int out_size, void* d_ws, size_t ws_size,
                              hipStream_t stream) {
    const float* tokens = (const float*)d_in[0];
    const float* ln_w   = (const float*)d_in[1];
    const float* ln_b   = (const float*)d_in[2];
    const float* wq     = (const float*)d_in[3];
    const float* wk     = (const float*)d_in[4];
    const float* wv     = (const float*)d_in[5];
    const float* wo     = (const float*)d_in[6];
    const float* lq1    = (const float*)d_in[7];
    const float* lk1    = (const float*)d_in[8];
    const float* lq2    = (const float*)d_in[9];
    const float* lk2    = (const float*)d_in[10];
    const float* sigs   = (const float*)d_in[11];
    const float* sign   = (const float*)d_in[12];
    const float* hn_w   = (const float*)d_in[13];
    const float* hn_b   = (const float*)d_in[14];

    const size_t n_qk = (size_t)BH * TSEQ * 64;   // 4.19M
    unsigned short* Qg      = (unsigned short*)d_ws;
    unsigned short* Kg      = Qg + n_qk;
    unsigned short* Vtg     = Kg + n_qk;
    unsigned short* WqkvT   = Vtg + n_qk;         // [768][128]
    unsigned short* WoT     = WqkvT + 768 * 128;  // [128][256]
    float*          scal    = (float*)(WoT + 128 * 256);

    k_prep<<<dim3(32), dim3(256), 0, stream>>>(
        wq, wk, wv, wo, lq1, lk1, lq2, lk2, sigs, sign, WqkvT, WoT, scal);
    k_qkv<<<dim3(BATCH * TSEQ / 32), dim3(256), 0, stream>>>(
        tokens, ln_w, ln_b, WqkvT, Qg, Kg, Vtg);
    k_attn2<<<dim3(512), dim3(256), 0, stream>>>(
        Qg, Kg, Vtg, scal, hn_w, hn_b, WoT, tokens, (float*)d_out);
}

// Round 15
// 60.823 us; speedup vs baseline: 1.3592x; 1.3592x over previous
//
#include <hip/hip_runtime.h>
#include <hip/hip_bf16.h>

#define TSEQ 2048
#define BATCH 8
#define NHEAD 4
#define BH (BATCH*NHEAD)
#define HD 32
#define SCALE 0.17677669529663687f   /* 1/sqrt(32) */
#define L2E   1.4426950408889634f
#define SCALE2 (SCALE * L2E)
#define LAMBDA_INIT 0.8f
#define LN_EPS 1e-5f

#if __has_builtin(__builtin_amdgcn_exp2f)
#define EXP2F(x) __builtin_amdgcn_exp2f(x)
#else
#define EXP2F(x) __expf((x) * 0.6931471805599453f)
#endif

typedef __attribute__((ext_vector_type(8))) short short8;
typedef __attribute__((ext_vector_type(4))) float f32x4;

// native bf16 convert (RTNE) — compiler emits v_cvt_pk_bf16_f32 pairs
static __device__ __forceinline__ unsigned short f2bf(float x) {
    union { __hip_bfloat16 h; unsigned short u; } cv;
    cv.h = __float2bfloat16(x);
    return cv.u;
}

// ---------------- Kernel P: weight transpose + bf16 cast + scalars ------
__global__ __launch_bounds__(256) void k_prep(
    const float* __restrict__ wq, const float* __restrict__ wk,
    const float* __restrict__ wv, const float* __restrict__ wo,
    const float* __restrict__ lq1, const float* __restrict__ lk1,
    const float* __restrict__ lq2, const float* __restrict__ lk2,
    const float* __restrict__ sig_s_p, const float* __restrict__ sig_n_p,
    unsigned short* __restrict__ WqkvT, unsigned short* __restrict__ WoT,
    float* __restrict__ scal)
{
    __shared__ float xt[64][65];
    const int bid = blockIdx.x, tid = threadIdx.x;

    if (bid == 0 && tid == 0) {
        float d1 = 0.f, d2 = 0.f;
        for (int i = 0; i < HD; i++) { d1 += lq1[i] * lk1[i]; d2 += lq2[i] * lk2[i]; }
        float lam = __expf(d1) - __expf(d2) + LAMBDA_INIT;
        float ss = fmaxf(sig_s_p[0], 1.f);
        float sn = fmaxf(sig_n_p[0], 1.f);
        int W = (int)ceilf(fmaxf(ss, sn) * 6.f);
        W = (W + 31) & ~31;
        if (W < 64) W = 64;
        scal[0] = lam;
        scal[1] = -0.5f / (ss * ss) * L2E;   // pre-scaled for exp2
        scal[2] = -0.5f / (sn * sn) * L2E;
        scal[3] = (float)W;
    }

    const float* src; int srcN, k0, nsrc0, dstK;
    unsigned short* dst;
    if (bid < 24) {
        int ntile = bid >> 1, ktile = bid & 1;
        int gn0 = ntile * 64; k0 = ktile * 64;
        int mat = gn0 >> 8;
        src = (mat == 0) ? wq : (mat == 1 ? wk : wv);
        srcN = 256; nsrc0 = gn0 & 255;
        dst = WqkvT + (size_t)gn0 * 128; dstK = 128;
    } else {
        int b2 = bid - 24;
        int ntile = b2 >> 2, ktile = b2 & 3;
        int gn0 = ntile * 64; k0 = ktile * 64;
        src = wo; srcN = 128; nsrc0 = gn0;
        dst = WoT + (size_t)gn0 * 256; dstK = 256;
    }
    {
        int r = tid >> 2, cs = tid & 3;
        const float* sp = src + (size_t)(k0 + r) * srcN + nsrc0 + cs * 16;
        #pragma unroll
        for (int j = 0; j < 4; j++) {
            float4 v = *(const float4*)(sp + j * 4);
            xt[r][cs * 16 + j * 4 + 0] = v.x;
            xt[r][cs * 16 + j * 4 + 1] = v.y;
            xt[r][cs * 16 + j * 4 + 2] = v.z;
            xt[r][cs * 16 + j * 4 + 3] = v.w;
        }
    }
    __syncthreads();
    {
        int n = tid >> 2, ks = tid & 3;
        short8 o0, o1;
        #pragma unroll
        for (int j = 0; j < 8; j++) {
            o0[j] = (short)f2bf(xt[ks * 16 + j][n]);
            o1[j] = (short)f2bf(xt[ks * 16 + 8 + j][n]);
        }
        unsigned short* dp = dst + (size_t)n * dstK + k0 + ks * 16;
        *(short8*)dp = o0;
        *(short8*)(dp + 8) = o1;
    }
}

// ---------------- Kernel A: LayerNorm + QKV projection (MFMA) ----------
__global__ __launch_bounds__(256) void k_qkv(
    const float* __restrict__ tokens, const float* __restrict__ ln_w,
    const float* __restrict__ ln_b, const unsigned short* __restrict__ WqkvT,
    unsigned short* __restrict__ Qg, unsigned short* __restrict__ Kg,
    unsigned short* __restrict__ Vtg)
{
    __shared__ unsigned short x_lds[32][132];
    __shared__ unsigned short c_lds[4][16][68];
    const int tid = threadIdx.x;
    const int r0 = blockIdx.x * 32;

    {
        int row = tid >> 3, sub = tid & 7;
        const float* tr = tokens + (size_t)(r0 + row) * 128 + sub * 16;
        float v[16]; float s = 0.f, sq = 0.f;
        #pragma unroll
        for (int j = 0; j < 16; j += 4) {
            float4 t4 = *(const float4*)(tr + j);
            v[j] = t4.x; v[j + 1] = t4.y; v[j + 2] = t4.z; v[j + 3] = t4.w;
        }
        #pragma unroll
        for (int j = 0; j < 16; j++) { s += v[j]; sq += v[j] * v[j]; }
        #pragma unroll
        for (int m = 1; m < 8; m <<= 1) { s += __shfl_xor(s, m, 64); sq += __shfl_xor(sq, m, 64); }
        float mean = s * (1.f / 128.f);
        float var  = sq * (1.f / 128.f) - mean * mean;
        float rstd = rsqrtf(var + LN_EPS);
        short8 o0, o1;
        #pragma unroll
        for (int j = 0; j < 8; j++) {
            int c0 = sub * 16 + j, c1 = sub * 16 + 8 + j;
            o0[j] = (short)f2bf((v[j] - mean) * rstd * ln_w[c0] + ln_b[c0]);
            o1[j] = (short)f2bf((v[8 + j] - mean) * rstd * ln_w[c1] + ln_b[c1]);
        }
        *(short8*)&x_lds[row][sub * 16] = o0;
        *(short8*)&x_lds[row][sub * 16 + 8] = o1;
    }
    __syncthreads();

    const int w = tid >> 6, lane = tid & 63;
    const int lg = lane >> 4, li = lane & 15;
    const int rt = w >> 1, ch = w & 1;

    short8 a[4];
    #pragma unroll
    for (int kc = 0; kc < 4; kc++)
        a[kc] = *(const short8*)&x_lds[rt * 16 + li][kc * 32 + lg * 8];

    const int b   = r0 >> 11;
    const int tw0 = (r0 & 2047) + rt * 16;

    #pragma unroll
    for (int cc = 0; cc < 6; cc++) {
        f32x4 acc[4] = {};
        #pragma unroll
        for (int t = 0; t < 4; t++) {
            int n0 = ch * 384 + cc * 64 + t * 16;
            const unsigned short* bp = WqkvT + (size_t)(n0 + li) * 128 + lg * 8;
            #pragma unroll
            for (int kc = 0; kc < 4; kc++) {
                short8 bf = *(const short8*)(bp + kc * 32);
                acc[t] = __builtin_amdgcn_mfma_f32_16x16x32_bf16(a[kc], bf, acc[t], 0, 0, 0);
            }
        }
        #pragma unroll
        for (int t = 0; t < 4; t++)
            #pragma unroll
            for (int r = 0; r < 4; r++)
                c_lds[w][lg * 4 + r][t * 16 + li] = f2bf(acc[t][r]);

        int gc = ch * 6 + cc;
        int kind = gc >> 2, h = gc & 3;
        size_t bhh = (size_t)(b * NHEAD + h);
        if (kind < 2) {
            unsigned short* base = (kind == 0) ? Qg : Kg;
            int row = lane >> 2, seg = lane & 3;
            unsigned short* dp = base + (bhh * TSEQ + tw0 + row) * 64 + seg * 16;
            *(short8*)dp       = *(const short8*)&c_lds[w][row][seg * 16];
            *(short8*)(dp + 8) = *(const short8*)&c_lds[w][row][seg * 16 + 8];
        } else {
            int d = lane;
            short8 v0, v1;
            #pragma unroll
            for (int j = 0; j < 8; j++) {
                v0[j] = (short)c_lds[w][j][d];
                v1[j] = (short)c_lds[w][8 + j][d];
            }
            unsigned short* dp = Vtg + (bhh * 64 + d) * TSEQ + tw0;
            *(short8*)dp = v0;
            *(short8*)(dp + 8) = v1;
        }
    }
}

// ---- Kernel B: fused banded differential attention + wo projection ----
// Best-known-good (R7/R8): 4 waves = 4 heads, 32 q rows/wave, uniform W=6*sigma
// band for both states, single K prefetch, early V issue, fused head-LN +
// wo GEMM + residual. XCD mapping: b = bid&7 pins batch K/V to one XCD L2.
__global__ __launch_bounds__(256) void k_attn2(
    const unsigned short* __restrict__ Qg, const unsigned short* __restrict__ Kg,
    const unsigned short* __restrict__ Vtg,
    const float* __restrict__ scal,
    const float* __restrict__ hn_w, const float* __restrict__ hn_b,
    const unsigned short* __restrict__ WoT, const float* __restrict__ tokens,
    float* __restrict__ out)
{
    __shared__ unsigned short p_lds[4][2][32][36];
    __shared__ unsigned short ao[32][264];

    const int tid  = threadIdx.x;
    const int w    = tid >> 6;        // wave = head
    const int lane = tid & 63;
    const int lg   = lane >> 4;
    const int li   = lane & 15;

    const int b  = blockIdx.x & 7;    // XCD-aware: batch pinned to XCD
    const int qw = (blockIdx.x >> 3) * 32;
    const int bh = b * NHEAD + w;

    const float lam = scal[0];
    const float c1  = scal[1];        // includes log2(e)
    const float c2  = scal[2];
    const int   W   = (int)scal[3];

    int lo = qw - W; if (lo < 0) lo = 0; lo &= ~31;
    int hi = qw + 32 + W; hi = (hi + 31) & ~31; if (hi > TSEQ) hi = TSEQ;

    short8 q1[2], q2[2];
    #pragma unroll
    for (int qt = 0; qt < 2; qt++) {
        const unsigned short* qp = Qg + ((size_t)bh * TSEQ + (qw + qt * 16 + li)) * 64;
        q1[qt] = *(const short8*)(qp + lg * 8);
        q2[qt] = *(const short8*)(qp + 32 + lg * 8);
    }

    const unsigned short* kbase = Kg  + ((size_t)bh * TSEQ + li) * 64 + lg * 8;
    const unsigned short* vbase = Vtg + ((size_t)bh * 64 + li) * TSEQ + lg * 8;

    f32x4 acc1[2][4] = {}, acc2[2][4] = {};
    float ls1[2][4] = {}, ls2[2][4] = {};
    const f32x4 zero4 = {0.f, 0.f, 0.f, 0.f};

    // prefetch K(lo)
    short8 kf1c[2], kf2c[2];
    {
        const unsigned short* kp = kbase + (size_t)lo * 64;
        kf1c[0] = *(const short8*)(kp);
        kf2c[0] = *(const short8*)(kp + 32);
        kf1c[1] = *(const short8*)(kp + 1024);
        kf2c[1] = *(const short8*)(kp + 1024 + 32);
    }

    for (int kv = lo; kv < hi; kv += 32) {
        // V(kv) issued early: latency hides under QK + exp
        const unsigned short* vp = vbase + kv;
        short8 vf[4];
        #pragma unroll
        for (int dt = 0; dt < 4; dt++)
            vf[dt] = *(const short8*)(vp + (size_t)dt * 16 * TSEQ);

        // K(kv+32) prefetch (uniform predicate)
        short8 kf1n[2], kf2n[2];
        if (kv + 32 < hi) {
            const unsigned short* kp = kbase + (size_t)(kv + 32) * 64;
            kf1n[0] = *(const short8*)(kp);
            kf2n[0] = *(const short8*)(kp + 32);
            kf1n[1] = *(const short8*)(kp + 1024);
            kf2n[1] = *(const short8*)(kp + 1024 + 32);
        }

        #pragma unroll
        for (int qt = 0; qt < 2; qt++) {
            f32x4 s1[2], s2[2];
            #pragma unroll
            for (int kt = 0; kt < 2; kt++) {
                s1[kt] = __builtin_amdgcn_mfma_f32_16x16x32_bf16(q1[qt], kf1c[kt], zero4, 0, 0, 0);
                s2[kt] = __builtin_amdgcn_mfma_f32_16x16x32_bf16(q2[qt], kf2c[kt], zero4, 0, 0, 0);
            }
            const float rb = (float)(kv + li - qw - qt * 16 - 4 * lg);
            #pragma unroll
            for (int kt = 0; kt < 2; kt++) {
                #pragma unroll
                for (int r = 0; r < 4; r++) {
                    float rel = rb + (float)(16 * kt - r);
                    float rr  = rel * rel;
                    float e1  = EXP2F(fmaf(s1[kt][r], SCALE2, c1 * rr));
                    float e2  = EXP2F(fmaf(s2[kt][r], SCALE2, c2 * rr));
                    ls1[qt][r] += e1;
                    ls2[qt][r] += e2;
                    p_lds[w][0][qt * 16 + lg * 4 + r][kt * 16 + li] = f2bf(e1);
                    p_lds[w][1][qt * 16 + lg * 4 + r][kt * 16 + li] = f2bf(e2);
                }
            }
        }

        #pragma unroll
        for (int qt = 0; qt < 2; qt++) {
            short8 pa1 = *(const short8*)&p_lds[w][0][qt * 16 + li][lg * 8];
            short8 pa2 = *(const short8*)&p_lds[w][1][qt * 16 + li][lg * 8];
            #pragma unroll
            for (int dt = 0; dt < 4; dt++) {
                acc1[qt][dt] = __builtin_amdgcn_mfma_f32_16x16x32_bf16(pa1, vf[dt], acc1[qt][dt], 0, 0, 0);
                acc2[qt][dt] = __builtin_amdgcn_mfma_f32_16x16x32_bf16(pa2, vf[dt], acc2[qt][dt], 0, 0, 0);
            }
        }

        kf1c[0] = kf1n[0]; kf1c[1] = kf1n[1];
        kf2c[0] = kf2n[0]; kf2c[1] = kf2n[1];
    }

    #pragma unroll
    for (int qt = 0; qt < 2; qt++)
        #pragma unroll
        for (int r = 0; r < 4; r++) {
            #pragma unroll
            for (int m = 1; m < 16; m <<= 1) {
                ls1[qt][r] += __shfl_xor(ls1[qt][r], m, 64);
                ls2[qt][r] += __shfl_xor(ls2[qt][r], m, 64);
            }
        }

    {
        float hw[4], hb[4];
        #pragma unroll
        for (int t = 0; t < 4; t++) { hw[t] = hn_w[t * 16 + li]; hb[t] = hn_b[t * 16 + li]; }

        #pragma unroll
        for (int qt = 0; qt < 2; qt++) {
            #pragma unroll
            for (int r = 0; r < 4; r++) {
                float il1 = 1.f / ls1[qt][r];
                float il2 = lam / ls2[qt][r];
                float o[4];
                float s = 0.f, sq = 0.f;
                #pragma unroll
                for (int t = 0; t < 4; t++) {
                    o[t] = acc1[qt][t][r] * il1 - acc2[qt][t][r] * il2;
                    s += o[t]; sq += o[t] * o[t];
                }
                #pragma unroll
                for (int m = 1; m < 16; m <<= 1) { s += __shfl_xor(s, m, 64); sq += __shfl_xor(sq, m, 64); }
                float mean = s * (1.f / 64.f);
                float var  = sq * (1.f / 64.f) - mean * mean;
                float rstd = rsqrtf(var + LN_EPS);
                int arow = qt * 16 + lg * 4 + r;
                #pragma unroll
                for (int t = 0; t < 4; t++) {
                    ao[arow][w * 64 + t * 16 + li] =
                        f2bf(((o[t] - mean) * rstd * hw[t] + hb[t]) * 0.2f);
                }
            }
        }
    }
    __syncthreads();

    // ---- wo GEMM: 32 rows x 256 k x 128 cols; wave w does cols [w*32, w*32+32)
    const int row0 = b * TSEQ + qw;
    #pragma unroll
    for (int c2 = 0; c2 < 2; c2++) {
        const int ct = w * 2 + c2;
        short8 bfr[8];
        const unsigned short* bp = WoT + (size_t)(ct * 16 + li) * 256 + lg * 8;
        #pragma unroll
        for (int kc = 0; kc < 8; kc++) bfr[kc] = *(const short8*)(bp + kc * 32);

        #pragma unroll
        for (int qt = 0; qt < 2; qt++) {
            f32x4 acc = {};
            #pragma unroll
            for (int kc = 0; kc < 8; kc++) {
                short8 af = *(const short8*)&ao[qt * 16 + li][kc * 32 + lg * 8];
                acc = __builtin_amdgcn_mfma_f32_16x16x32_bf16(af, bfr[kc], acc, 0, 0, 0);
            }
            #pragma unroll
            for (int r = 0; r < 4; r++) {
                size_t idx = (size_t)(row0 + qt * 16 + lg * 4 + r) * 128 + ct * 16 + li;
                out[idx] = tokens[idx] + acc[r];
            }
        }
    }
}

extern "C" void kernel_launch(void* const* d_in, const int* in_sizes, int n_in,
                              void* d_out, int out_size, void* d_ws, size_t ws_size,
                              hipStream_t stream) {
    const float* tokens = (const float*)d_in[0];
    const float* ln_w   = (const float*)d_in[1];
    const float* ln_b   = (const float*)d_in[2];
    const float* wq     = (const float*)d_in[3];
    const float* wk     = (const float*)d_in[4];
    const float* wv     = (const float*)d_in[5];
    const float* wo     = (const float*)d_in[6];
    const float* lq1    = (const float*)d_in[7];
    const float* lk1    = (const float*)d_in[8];
    const float* lq2    = (const float*)d_in[9];
    const float* lk2    = (const float*)d_in[10];
    const float* sigs   = (const float*)d_in[11];
    const float* sign   = (const float*)d_in[12];
    const float* hn_w   = (const float*)d_in[13];
    const float* hn_b   = (const float*)d_in[14];

    const size_t n_qk = (size_t)BH * TSEQ * 64;   // 4.19M
    unsigned short* Qg      = (unsigned short*)d_ws;
    unsigned short* Kg      = Qg + n_qk;
    unsigned short* Vtg     = Kg + n_qk;
    unsigned short* WqkvT   = Vtg + n_qk;         // [768][128]
    unsigned short* WoT     = WqkvT + 768 * 128;  // [128][256]
    float*          scal    = (float*)(WoT + 128 * 256);

    k_prep<<<dim3(32), dim3(256), 0, stream>>>(
        wq, wk, wv, wo, lq1, lk1, lq2, lk2, sigs, sign, WqkvT, WoT, scal);
    k_qkv<<<dim3(BATCH * TSEQ / 32), dim3(256), 0, stream>>>(
        tokens, ln_w, ln_b, WqkvT, Qg, Kg, Vtg);
    k_attn2<<<dim3(512), dim3(256), 0, stream>>>(
        Qg, Kg, Vtg, scal, hn_w, hn_b, WoT, tokens, (float*)d_out);
}